// Round 1
// baseline (2127.953 us; speedup 1.0000x reference)
//
#include <hip/hip_runtime.h>
#include <hip/hip_bf16.h>

#define N_POINTS 2000000
#define NLEV 16
#define LOG2_T 19
#define T_MASK ((1u << LOG2_T) - 1u)
#define TF ((size_t)(1u << LOG2_T) * 2)   // floats per (part, level) slice

// floor(16 * 1.5^l) for l = 0..15, computed in double precision
__constant__ float c_res[NLEV] = {
    16.f, 24.f, 36.f, 54.f, 81.f, 121.f, 182.f, 273.f,
    410.f, 615.f, 922.f, 1383.f, 2075.f, 3113.f, 4670.f, 7006.f
};

__global__ __launch_bounds__(256) void hash_enc_kernel(
        const float* __restrict__ coords,
        const float* __restrict__ tables,
        float* __restrict__ out) {
    const int tid = blockIdx.x * blockDim.x + threadIdx.x;
    if (tid >= N_POINTS * NLEV) return;
    const int n = tid >> 4;      // point index
    const int l = tid & 15;      // level index

    const float cx = coords[n * 3 + 0];
    const float cy = coords[n * 3 + 1];
    const float cz = coords[n * 3 + 2];

    // partition: cell = clip(floor(c*2), 0, 1); flat = cx*4 + cy*2 + cz
    int px = (int)floorf(cx * 2.0f); px = px < 0 ? 0 : (px > 1 ? 1 : px);
    int py = (int)floorf(cy * 2.0f); py = py < 0 ? 0 : (py > 1 ? 1 : py);
    int pz = (int)floorf(cz * 2.0f); pz = pz < 0 ? 0 : (pz > 1 ? 1 : pz);
    const int flat = px * 4 + py * 2 + pz;

    const float* __restrict__ tb = tables + ((size_t)(flat * NLEV + l)) * TF;

    const float res = c_res[l];
    const float sx = cx * res, sy = cy * res, sz = cz * res;
    const float fx0 = floorf(sx), fy0 = floorf(sy), fz0 = floorf(sz);
    const float fx = sx - fx0, fy = sy - fy0, fz = sz - fz0;

    const uint32_t ix = (uint32_t)fx0;
    const uint32_t iy = (uint32_t)fy0;
    const uint32_t iz = (uint32_t)fz0;

    const uint32_t hx0 = ix;                             // * PRIME0 (=1)
    const uint32_t hx1 = ix + 1u;
    const uint32_t hy0 = iy * 2654435761u;
    const uint32_t hy1 = (iy + 1u) * 2654435761u;
    const uint32_t hz0 = iz * 805459861u;
    const uint32_t hz1 = (iz + 1u) * 805459861u;

    const float gx0 = 1.0f - fx, gy0 = 1.0f - fy, gz0 = 1.0f - fz;

    float s0 = 0.0f, s1 = 0.0f;
    #pragma unroll
    for (int c = 0; c < 8; ++c) {
        const uint32_t h = (((c & 1) ? hx1 : hx0)
                          ^ ((c & 2) ? hy1 : hy0)
                          ^ ((c & 4) ? hz1 : hz0)) & T_MASK;
        const float2 e = *(const float2*)(tb + (size_t)h * 2);
        // weight order matches jnp.prod over last axis: ((wx*wy)*wz)
        float w = ((c & 1) ? fx : gx0) * ((c & 2) ? fy : gy0);
        w = w * ((c & 4) ? fz : gz0);
        s0 += w * e.x;
        s1 += w * e.y;
    }

    // out[n, l*2 .. l*2+1] -> flat offset n*32 + l*2 == tid*2, 8B aligned
    float2* __restrict__ o = (float2*)out;
    o[tid] = make_float2(s0, s1);
}

extern "C" void kernel_launch(void* const* d_in, const int* in_sizes, int n_in,
                              void* d_out, int out_size, void* d_ws, size_t ws_size,
                              hipStream_t stream) {
    const float* coords = (const float*)d_in[0];
    const float* tables = (const float*)d_in[1];
    float* out = (float*)d_out;

    const int total = N_POINTS * NLEV;
    const int block = 256;
    const int grid = (total + block - 1) / block;
    hash_enc_kernel<<<grid, block, 0, stream>>>(coords, tables, out);
}

// Round 3
// 1691.606 us; speedup vs baseline: 1.2579x; 1.2579x over previous
//
#include <hip/hip_runtime.h>
#include <hip/hip_bf16.h>

#define N_POINTS 2000000
#define NLEV 16
#define LOG2_T 19
#define T_MASK ((1u << LOG2_T) - 1u)
#define TF ((size_t)(1u << LOG2_T) * 2)   // floats per (part, level) slice

#define PTS_PER_BLK 256
#define CHUNKS ((N_POINTS + PTS_PER_BLK - 1) / PTS_PER_BLK)   // 7813

typedef float f32x2 __attribute__((ext_vector_type(2)));

// floor(16 * 1.5^l) for l = 0..15 (double-precision derived, exact in fp32)
__constant__ float c_res[NLEV] = {
    16.f, 24.f, 36.f, 54.f, 81.f, 121.f, 182.f, 273.f,
    410.f, 615.f, 922.f, 1383.f, 2075.f, 3113.f, 4670.f, 7006.f
};

// ---------- main kernel: level-major, writes ws[l][n] (f32x2, coalesced) -----
__global__ __launch_bounds__(256) void hash_enc_lvlmajor(
        const float* __restrict__ coords,
        const float* __restrict__ tables,
        f32x2* __restrict__ ws) {
    const int b = blockIdx.x;
    const int l = b / CHUNKS;              // level = slowest digit -> temporal locality
    const int n = (b % CHUNKS) * PTS_PER_BLK + threadIdx.x;
    if (n >= N_POINTS) return;

    const float cx = coords[n * 3 + 0];
    const float cy = coords[n * 3 + 1];
    const float cz = coords[n * 3 + 2];

    int px = (int)floorf(cx * 2.0f); px = px < 0 ? 0 : (px > 1 ? 1 : px);
    int py = (int)floorf(cy * 2.0f); py = py < 0 ? 0 : (py > 1 ? 1 : py);
    int pz = (int)floorf(cz * 2.0f); pz = pz < 0 ? 0 : (pz > 1 ? 1 : pz);
    const int flat = px * 4 + py * 2 + pz;

    const float* __restrict__ tb = tables + ((size_t)(flat * NLEV + l)) * TF;

    const float res = c_res[l];
    const float sx = cx * res, sy = cy * res, sz = cz * res;
    const float fx0 = floorf(sx), fy0 = floorf(sy), fz0 = floorf(sz);
    const float fx = sx - fx0, fy = sy - fy0, fz = sz - fz0;

    const uint32_t ix = (uint32_t)fx0;
    const uint32_t iy = (uint32_t)fy0;
    const uint32_t iz = (uint32_t)fz0;

    const uint32_t hx0 = ix;               // PRIME0 == 1
    const uint32_t hx1 = ix + 1u;
    const uint32_t hy0 = iy * 2654435761u;
    const uint32_t hy1 = (iy + 1u) * 2654435761u;
    const uint32_t hz0 = iz * 805459861u;
    const uint32_t hz1 = (iz + 1u) * 805459861u;

    const float gx = 1.0f - fx, gy = 1.0f - fy, gz = 1.0f - fz;

    float s0 = 0.0f, s1 = 0.0f;
    #pragma unroll
    for (int c = 0; c < 8; ++c) {
        const uint32_t h = (((c & 1) ? hx1 : hx0)
                          ^ ((c & 2) ? hy1 : hy0)
                          ^ ((c & 4) ? hz1 : hz0)) & T_MASK;
        const f32x2 e = *(const f32x2*)(tb + (size_t)h * 2);
        float w = ((c & 1) ? fx : gx) * ((c & 2) ? fy : gy);
        w = w * ((c & 4) ? fz : gz);
        s0 += w * e.x;
        s1 += w * e.y;
    }

    // ws[l][n] — coalesced; non-temporal: don't evict table lines from L2/L3
    f32x2 r; r.x = s0; r.y = s1;
    __builtin_nontemporal_store(r, &ws[(size_t)l * N_POINTS + n]);
}

// ---------- transpose: ws[l][n] -> out[n][l] (both sides coalesced) ----------
__global__ __launch_bounds__(256) void transpose_lvl_to_pt(
        const f32x2* __restrict__ ws,
        f32x2* __restrict__ out) {
    __shared__ f32x2 tile[NLEV][PTS_PER_BLK + 1];   // +1 pad: conflict-light

    const int n0 = blockIdx.x * PTS_PER_BLK;
    const int t = threadIdx.x;

    // phase A: 16 coalesced row reads
    #pragma unroll
    for (int l = 0; l < NLEV; ++l) {
        const int n = n0 + t;
        if (n < N_POINTS)
            tile[l][t] = __builtin_nontemporal_load(&ws[(size_t)l * N_POINTS + n]);
    }
    __syncthreads();

    // phase B: write point-major, l fastest across lanes -> fully coalesced
    const int ll = t & 15;
    const int hi = t >> 4;                 // 0..15
    #pragma unroll
    for (int j = 0; j < NLEV; ++j) {
        const int pp = j * 16 + hi;        // covers 0..255 across j
        const int n = n0 + pp;
        if (n < N_POINTS)
            __builtin_nontemporal_store(tile[ll][pp], &out[(size_t)n * NLEV + ll]);
    }
}

// ---------- fallback (round-1 kernel) if ws too small ------------------------
__global__ __launch_bounds__(256) void hash_enc_direct(
        const float* __restrict__ coords,
        const float* __restrict__ tables,
        float* __restrict__ out) {
    const int tid = blockIdx.x * blockDim.x + threadIdx.x;
    if (tid >= N_POINTS * NLEV) return;
    const int n = tid >> 4;
    const int l = tid & 15;

    const float cx = coords[n * 3 + 0];
    const float cy = coords[n * 3 + 1];
    const float cz = coords[n * 3 + 2];

    int px = (int)floorf(cx * 2.0f); px = px < 0 ? 0 : (px > 1 ? 1 : px);
    int py = (int)floorf(cy * 2.0f); py = py < 0 ? 0 : (py > 1 ? 1 : py);
    int pz = (int)floorf(cz * 2.0f); pz = pz < 0 ? 0 : (pz > 1 ? 1 : pz);
    const int flat = px * 4 + py * 2 + pz;

    const float* __restrict__ tb = tables + ((size_t)(flat * NLEV + l)) * TF;

    const float res = c_res[l];
    const float sx = cx * res, sy = cy * res, sz = cz * res;
    const float fx0 = floorf(sx), fy0 = floorf(sy), fz0 = floorf(sz);
    const float fx = sx - fx0, fy = sy - fy0, fz = sz - fz0;

    const uint32_t ix = (uint32_t)fx0;
    const uint32_t iy = (uint32_t)fy0;
    const uint32_t iz = (uint32_t)fz0;

    const uint32_t hx0 = ix, hx1 = ix + 1u;
    const uint32_t hy0 = iy * 2654435761u, hy1 = (iy + 1u) * 2654435761u;
    const uint32_t hz0 = iz * 805459861u,  hz1 = (iz + 1u) * 805459861u;

    const float gx = 1.0f - fx, gy = 1.0f - fy, gz = 1.0f - fz;

    float s0 = 0.0f, s1 = 0.0f;
    #pragma unroll
    for (int c = 0; c < 8; ++c) {
        const uint32_t h = (((c & 1) ? hx1 : hx0)
                          ^ ((c & 2) ? hy1 : hy0)
                          ^ ((c & 4) ? hz1 : hz0)) & T_MASK;
        const f32x2 e = *(const f32x2*)(tb + (size_t)h * 2);
        float w = ((c & 1) ? fx : gx) * ((c & 2) ? fy : gy);
        w = w * ((c & 4) ? fz : gz);
        s0 += w * e.x;
        s1 += w * e.y;
    }
    f32x2 r; r.x = s0; r.y = s1;
    ((f32x2*)out)[tid] = r;
}

extern "C" void kernel_launch(void* const* d_in, const int* in_sizes, int n_in,
                              void* d_out, int out_size, void* d_ws, size_t ws_size,
                              hipStream_t stream) {
    const float* coords = (const float*)d_in[0];
    const float* tables = (const float*)d_in[1];

    const size_t ws_needed = (size_t)N_POINTS * NLEV * sizeof(f32x2);  // 256 MB

    if (ws_size >= ws_needed) {
        f32x2* ws = (f32x2*)d_ws;
        hash_enc_lvlmajor<<<NLEV * CHUNKS, 256, 0, stream>>>(coords, tables, ws);
        transpose_lvl_to_pt<<<CHUNKS, 256, 0, stream>>>(ws, (f32x2*)d_out);
    } else {
        const int total = N_POINTS * NLEV;
        hash_enc_direct<<<(total + 255) / 256, 256, 0, stream>>>(coords, tables, (float*)d_out);
    }
}